// Round 10
// baseline (264.374 us; speedup 1.0000x reference)
//
#include <hip/hip_runtime.h>
#include <hip/hip_bf16.h>
#include <hip/hip_fp8.h>
#include <stdint.h>

typedef __bf16 bf16;
typedef __attribute__((ext_vector_type(8))) short short8;
typedef __attribute__((ext_vector_type(4))) float f32x4;
typedef __attribute__((ext_vector_type(4))) bf16 bf16x4;
typedef __attribute__((ext_vector_type(8))) int int8v;
typedef __attribute__((ext_vector_type(4))) int int4v;

#define DIM 512
#define NBATCH 8
#define SEQ 2048

#define VMCNT(N) asm volatile("s_waitcnt vmcnt(" #N ")" ::: "memory")
#define CFENCE   asm volatile("" ::: "memory")

// async global->LDS, 16B per lane; LDS dest must be wave-uniform base + lane*16
__device__ __forceinline__ void gld_lds16(const void* g, void* l) {
    __builtin_amdgcn_global_load_lds(
        (const __attribute__((address_space(1))) void*)g,
        (__attribute__((address_space(3))) void*)l,
        16, 0, 0);
}

__device__ __forceinline__ unsigned char f32_to_e4m3(float v) {
#if __has_builtin(__builtin_amdgcn_cvt_pk_fp8_f32)
    return (unsigned char)(__builtin_amdgcn_cvt_pk_fp8_f32(v, v, 0, false) & 0xff);
#else
    return __hip_cvt_float_to_fp8(v, __HIP_SATFINITE, __HIP_E4M3);
#endif
}

// ---------------------------------------------------------------------------
// bf16 bt-GEMM: 128x128 tile, BK=64, double-buffered LDS (64 KB).
// R6-verified counted-vmcnt 2-barrier loop (worth ~12 us vs drain-0).
// MODE 2: C fp32 row-major [M][N], +bias  (out-projection).
// MODE 3: QKV split, all fp8(x32):
//         sub 0/1 (Q/K): row-major [16384][512] at Cv + sub*8388608.
//         sub 2 (V): written TRANSPOSED directly to Vt[(b*512+f)*2048+n].
// SWIZ 2: 1D grid, xcd=g&7; column-sibling blocks share an XCD (L2 reuse).
// ---------------------------------------------------------------------------
template <int MODE, int SWIZ>
__global__ __launch_bounds__(256) void gemm_bt(
    const bf16* __restrict__ A, const bf16* __restrict__ Bt,
    void* __restrict__ Cv, uint8_t* __restrict__ Vt,
    const float* __restrict__ bias, int N, int K, int gx)
{
    __shared__ bf16 smem[32768];         // 64 KB
    bf16* Asb = smem;
    bf16* Bsb = smem + 16384;

    int bx, by;
    {
        const unsigned g = blockIdx.x;
        const unsigned xcd = g & 7;
        const unsigned t = g >> 3;
        const unsigned per = (gridDim.x >> 3) / (unsigned)gx;
        by = xcd * per + t / (unsigned)gx;
        bx = t % (unsigned)gx;
    }

    const int tid  = threadIdx.x;
    const int lane = tid & 63;
    const int w    = tid >> 6;
    const int wr   = w >> 1;
    const int wc   = w & 1;
    const int lm   = lane & 15;
    const int lk   = lane >> 4;
    const int fs   = lm & 7;
    const int rq   = tid >> 3;
    const int pc   = tid & 7;
    const int scol = ((pc ^ (rq & 7)) * 8);

    const bf16* Ag = A + (size_t)(by * 128) * K;
    const bf16* Bg = Bt + (size_t)(bx * 128) * K;

    f32x4 acc[4][4];
#pragma unroll
    for (int i = 0; i < 4; ++i)
#pragma unroll
        for (int j = 0; j < 4; ++j)
            acc[i][j] = (f32x4){0.f, 0.f, 0.f, 0.f};

    auto stage = [&](int kb, int buf) {
#pragma unroll
        for (int t = 0; t < 4; ++t) {
            const int r = t * 32 + rq;
            gld_lds16(Ag + (size_t)r * K + kb + scol,
                      Asb + buf * 8192 + t * 2048 + tid * 8);
            gld_lds16(Bg + (size_t)r * K + kb + scol,
                      Bsb + buf * 8192 + t * 2048 + tid * 8);
        }
    };
    auto compute = [&](int buf) {
        const bf16* Ab = Asb + buf * 8192;
        const bf16* Bb = Bsb + buf * 8192;
#pragma unroll
        for (int s = 0; s < 2; ++s) {
            const int u = ((s * 4 + lk) ^ fs) * 8;
            short8 fa[4], fb[4];
#pragma unroll
            for (int i = 0; i < 4; ++i)
                fa[i] = *(const short8*)&Ab[(wr * 64 + i * 16 + lm) * 64 + u];
#pragma unroll
            for (int j = 0; j < 4; ++j)
                fb[j] = *(const short8*)&Bb[(wc * 64 + j * 16 + lm) * 64 + u];
#pragma unroll
            for (int i = 0; i < 4; ++i)
#pragma unroll
                for (int j = 0; j < 4; ++j)
                    acc[i][j] = __builtin_amdgcn_mfma_f32_16x16x32_bf16(
                        fa[i], fb[j], acc[i][j], 0, 0, 0);
        }
    };

    stage(0, 0);
    const int E = K >> 6;
#pragma unroll 2
    for (int e = 0; e < E; ++e) {
        const int p = e & 1;
        CFENCE;
        __builtin_amdgcn_s_barrier();    // WAR: buf p^1 readers done
        CFENCE;
        if (e + 1 < E) { stage((e + 1) << 6, p ^ 1); VMCNT(8); }
        else           { VMCNT(0); }
        CFENCE;
        __builtin_amdgcn_s_barrier();    // tile e published
        CFENCE;
        __builtin_amdgcn_s_setprio(1);
        compute(p);
        __builtin_amdgcn_s_setprio(0);
    }
    __syncthreads();                     // epilogue reuses smem

    // bias add
#pragma unroll
    for (int i = 0; i < 4; ++i)
#pragma unroll
        for (int j = 0; j < 4; ++j) {
            const int col = bx * 128 + wc * 64 + j * 16 + lm;
            const float bv = bias[col];
#pragma unroll
            for (int r = 0; r < 4; ++r)
                acc[i][j][r] += bv;
        }

    if (MODE == 2) {
        // fp32 out via LDS-coalesced float4 stores; ft = [64][132] floats
        float* ft = (float*)smem;
        float* outp = (float*)Cv;
#pragma unroll
        for (int h = 0; h < 2; ++h) {
            if (wr == h) {
#pragma unroll
                for (int i = 0; i < 4; ++i)
#pragma unroll
                    for (int j = 0; j < 4; ++j)
#pragma unroll
                        for (int r = 0; r < 4; ++r)
                            ft[(i * 16 + lk * 4 + r) * 132 + wc * 64 + j * 16 + lm] =
                                acc[i][j][r];
            }
            __syncthreads();
            const int rr = tid >> 5, cc = (tid & 31) * 4;
#pragma unroll
            for (int p = 0; p < 8; ++p) {
                const int row = p * 8 + rr;
                *(float4*)&outp[(size_t)(by * 128 + h * 64 + row) * N +
                                bx * 128 + cc] = *(const float4*)&ft[row * 132 + cc];
            }
            __syncthreads();
        }
        return;
    }

    // MODE 3
    const int sub  = (bx * 128) >> 9;          // 0=Q 1=K 2=V
    const int col0 = (bx * 128) & 511;

    if (sub == 2) {
        // V: transposed fp8 write -> Vt[(b*512 + col0+f)*2048 + n]
        const int b  = (by * 128) >> 11;
        const int n0 = (by * 128) & 2047;
        uint8_t* t8 = (uint8_t*)smem;
#pragma unroll
        for (int i = 0; i < 4; ++i)
#pragma unroll
            for (int j = 0; j < 4; ++j)
#pragma unroll
                for (int r = 0; r < 4; ++r) {
                    const int fl = wc * 64 + j * 16 + lm;      // feature
                    const int nl = wr * 64 + i * 16 + lk * 4 + r;  // token
                    t8[fl * 144 + nl] = f32_to_e4m3(32.0f * acc[i][j][r]);
                }
        __syncthreads();
        const int f = tid >> 1, nh = (tid & 1) * 64;
#pragma unroll
        for (int p = 0; p < 4; ++p) {
            const uint4 raw = *(const uint4*)&t8[f * 144 + nh + p * 16];
            *(uint4*)&Vt[((size_t)(b * 512 + col0 + f)) * 2048 +
                         n0 + nh + p * 16] = raw;
        }
        return;
    }

    // Q/K: row-major fp8 writer via LDS [64][144] tile halves
    uint8_t* d8 = (uint8_t*)Cv + (size_t)sub * 8388608;
    uint8_t* t8 = (uint8_t*)smem;
#pragma unroll
    for (int h = 0; h < 2; ++h) {
        if (wr == h) {
#pragma unroll
            for (int i = 0; i < 4; ++i)
#pragma unroll
                for (int j = 0; j < 4; ++j)
#pragma unroll
                    for (int r = 0; r < 4; ++r)
                        t8[(i * 16 + lk * 4 + r) * 144 + wc * 64 + j * 16 + lm] =
                            f32_to_e4m3(32.0f * acc[i][j][r]);
        }
        __syncthreads();
        const int rr = tid >> 3, cc = (tid & 7) * 16;
#pragma unroll
        for (int p = 0; p < 2; ++p) {
            const int row = p * 32 + rr;
            const uint4 raw = *(const uint4*)&t8[row * 144 + cc];
            *(uint4*)&d8[(size_t)(by * 128 + h * 64 + row) * 512 + col0 + cc] =
                raw;
        }
        __syncthreads();
    }
}

// ---------------------------------------------------------------------------
// FUSED ATTENTION (R8, resubmitted R10 to disambiguate R9's core-dump:
// full audit found no OOB/race; R7's structurally-identical 64-row version
// passed on HW). 32-row Q blocks, grid 512 (= 2 blocks/CU), 256 thr.
// Per kv-tile (128 tokens):
//   QK: fa from Q-LDS (chunk-swizzled), fb(K) direct-from-L2, 16 MFMA/wave;
//   exp -> psum (reg) + S8 bytes into swizzled Ss[32][128];
//   V-frags (8x 32B) issued BEFORE the barrier (in flight across it);
//   PV: fa from Ss, 16 MFMA/wave into opv[2][8].
// End: lm-shuffle psum + LDS-atomic rowsum, normalize, bf16 out via LDS.
// ---------------------------------------------------------------------------
__global__ __launch_bounds__(256) void attn_fused(
    const uint8_t* __restrict__ Q8, const uint8_t* __restrict__ K8,
    const uint8_t* __restrict__ Vt8, bf16* __restrict__ Ctx, float alpha)
{
    __shared__ uint8_t smem[33280];
    // [0,16384) Qs swz | [16384,20480) Ss swz | [20480,20608) rs
    // after main loop: whole smem reused as [32][520] bf16 out tile
    uint8_t* Qs = smem;
    uint8_t* Ss = smem + 16384;
    float*   rs = (float*)(smem + 20480);

    const unsigned g = blockIdx.x;
    const int bz  = g & 7;
    const int qr0 = (int)(g >> 3) * 32;

    const int tid  = threadIdx.x;
    const int lane = tid & 63;
    const int w    = tid >> 6;           // 0..3
    const int lm   = lane & 15;
    const int lk   = lane >> 4;
    const int c0   = ((2 * lk) ^ (lm & 7)) * 16;
    const int c1   = ((2 * lk + 1) ^ (lm & 7)) * 16;

    // ---- stage Q once (source pre-swizzled so LDS stays linear) ----
    {
        const uint8_t* Qg = Q8 + (size_t)(bz * SEQ + qr0) * DIM;
        const int R = tid >> 5;          // 0..7
        const int c = tid & 31;
        const int sc = (c ^ (R & 7)) * 16;
#pragma unroll
        for (int p = 0; p < 4; ++p)
            gld_lds16(Qg + (size_t)(p * 8 + R) * DIM + sc,
                      Qs + p * 4096 + tid * 16);
    }
    if (tid < 32) rs[tid] = 0.f;
    VMCNT(0);
    __syncthreads();

    f32x4 opv[2][8];
#pragma unroll
    for (int i = 0; i < 2; ++i)
#pragma unroll
        for (int j = 0; j < 8; ++j)
            opv[i][j] = (f32x4){0.f, 0.f, 0.f, 0.f};
    float psum[2][4];
#pragma unroll
    for (int i = 0; i < 2; ++i)
#pragma unroll
        for (int r = 0; r < 4; ++r)
            psum[i][r] = 0.f;

    const uint8_t* Kg = K8 + (size_t)(bz * SEQ) * DIM;
    const uint8_t* Vg = Vt8 + (size_t)(bz * DIM + w * 128) * (size_t)SEQ;

    for (int kv = 0; kv < 16; ++kv) {
        // ---- QK phase ----
        f32x4 sacc[2][2];
#pragma unroll
        for (int i = 0; i < 2; ++i)
#pragma unroll
            for (int jj = 0; jj < 2; ++jj)
                sacc[i][jj] = (f32x4){0.f, 0.f, 0.f, 0.f};
        const uint8_t* Kb = Kg + (size_t)(kv * 128 + w * 32) * DIM;
#pragma unroll
        for (int k = 0; k < 4; ++k) {
            int8v fa[2];
#pragma unroll
            for (int i = 0; i < 2; ++i) {
                const uint8_t* rp = Qs + (i * 16 + lm) * 512 + k * 128;
                const int4v lo = *(const int4v*)(rp + c0);
                const int4v hi = *(const int4v*)(rp + c1);
                fa[i] = (int8v){lo[0], lo[1], lo[2], lo[3],
                                hi[0], hi[1], hi[2], hi[3]};
            }
#pragma unroll
            for (int jj = 0; jj < 2; ++jj) {
                const uint8_t* kp = Kb + (size_t)(jj * 16 + lm) * DIM +
                                    k * 128 + 32 * lk;
                const int4v lo = *(const int4v*)kp;
                const int4v hi = *(const int4v*)(kp + 16);
                const int8v fb = (int8v){lo[0], lo[1], lo[2], lo[3],
                                         hi[0], hi[1], hi[2], hi[3]};
#pragma unroll
                for (int i = 0; i < 2; ++i)
                    sacc[i][jj] =
                        __builtin_amdgcn_mfma_scale_f32_16x16x128_f8f6f4(
                            fa[i], fb, sacc[i][jj], 0, 0, 0, 127, 0, 127);
            }
        }

        // ---- exp + rowsum partials + S8 -> swizzled LDS ----
#pragma unroll
        for (int i = 0; i < 2; ++i)
#pragma unroll
            for (int jj = 0; jj < 2; ++jj)
#pragma unroll
                for (int r = 0; r < 4; ++r) {
                    const float e = __expf(sacc[i][jj][r] * alpha);
                    psum[i][r] += e;
                    const int m = i * 16 + lk * 4 + r;
                    const int n = w * 32 + jj * 16 + lm;
                    Ss[m * 128 + (((n >> 4) ^ (m & 7)) << 4) + (n & 15)] =
                        f32_to_e4m3(e);
                }

        // ---- V fragments issued before the barrier (hide L2 latency) ----
        const uint8_t* Vb = Vg + kv * 128 + 32 * lk;
        int8v fbv[8];
#pragma unroll
        for (int j = 0; j < 8; ++j) {
            const uint8_t* vp = Vb + (size_t)(j * 16 + lm) * (size_t)SEQ;
            const int4v lo = *(const int4v*)vp;
            const int4v hi = *(const int4v*)(vp + 16);
            fbv[j] = (int8v){lo[0], lo[1], lo[2], lo[3],
                             hi[0], hi[1], hi[2], hi[3]};
        }
        __syncthreads();                 // S published (V loads drain here too)

        // ---- PV phase ----
        __builtin_amdgcn_s_setprio(1);
#pragma unroll
        for (int i = 0; i < 2; ++i) {
            const uint8_t* rp = Ss + (i * 16 + lm) * 128;
            const int4v lo = *(const int4v*)(rp + c0);
            const int4v hi = *(const int4v*)(rp + c1);
            const int8v fa = (int8v){lo[0], lo[1], lo[2], lo[3],
                                     hi[0], hi[1], hi[2], hi[3]};
#pragma unroll
            for (int j = 0; j < 8; ++j)
                opv[i][j] = __builtin_amdgcn_mfma_scale_f32_16x16x128_f8f6f4(
                    fa, fbv[j], opv[i][j], 0, 0, 0, 127, 0, 127);
        }
        __builtin_amdgcn_s_setprio(0);
        __syncthreads();                 // WAR: Ss rewritten next tile
    }

    // ---- block-local rowsum: reduce over lm, LDS atomics across waves ----
#pragma unroll
    for (int m = 1; m < 16; m <<= 1)
#pragma unroll
        for (int i = 0; i < 2; ++i)
#pragma unroll
            for (int r = 0; r < 4; ++r)
                psum[i][r] += __shfl_xor(psum[i][r], m);
    if (lm == 0) {
#pragma unroll
        for (int i = 0; i < 2; ++i)
#pragma unroll
            for (int r = 0; r < 4; ++r)
                atomicAdd(&rs[i * 16 + lk * 4 + r], psum[i][r]);
    }
    __syncthreads();
    float inv[2][4];
#pragma unroll
    for (int i = 0; i < 2; ++i)
#pragma unroll
        for (int r = 0; r < 4; ++r)
            inv[i][r] = 1.0f / (32.0f * rs[i * 16 + lk * 4 + r]);
    __syncthreads();                     // rs read; smem free for staging

    // ---- normalize + bf16 out via [32][520] LDS tile, coalesced store ----
    bf16* bt = (bf16*)smem;
#pragma unroll
    for (int i = 0; i < 2; ++i)
#pragma unroll
        for (int j = 0; j < 8; ++j)
#pragma unroll
            for (int r = 0; r < 4; ++r)
                bt[(i * 16 + lk * 4 + r) * 520 + w * 128 + j * 16 + lm] =
                    (bf16)(opv[i][j][r] * inv[i][r]);
    __syncthreads();
#pragma unroll
    for (int p = 0; p < 8; ++p) {
        const int row = p * 4 + (tid >> 6);
        const uint4 raw =
            *(const uint4*)((const uint8_t*)smem + row * 1040 + (tid & 63) * 16);
        *(uint4*)&Ctx[(size_t)(bz * SEQ + qr0 + row) * DIM + (tid & 63) * 8] =
            raw;
    }
}

// ---------------------------------------------------------------------------
__global__ __launch_bounds__(256) void cvt_f32_bf16(
    const float* __restrict__ x, bf16* __restrict__ o, int n4)
{
    const int i = blockIdx.x * 256 + threadIdx.x;
    if (i >= n4) return;
    const float4 v = ((const float4*)x)[i];
    bf16x4 b;
    b[0] = (bf16)v.x; b[1] = (bf16)v.y; b[2] = (bf16)v.z; b[3] = (bf16)v.w;
    ((bf16x4*)o)[i] = b;
}

// Weights transpose -> bf16; z==4 slice zeroes rowsum + packs bcat=bq|bk|bv.
__global__ __launch_bounds__(256) void transpose4(
    const float* __restrict__ Wq, const float* __restrict__ Wk,
    const float* __restrict__ Wv, const float* __restrict__ Wo,
    bf16* __restrict__ Wcat, bf16* __restrict__ Wto,
    const float* __restrict__ bq, const float* __restrict__ bk,
    const float* __restrict__ bv, float* __restrict__ bcat,
    float* __restrict__ rowsum)
{
    const int widx = blockIdx.z;
    const int t0 = threadIdx.x;
    if (widx == 4) {
        const int idx = (blockIdx.y * 8 + blockIdx.x) * 256 + t0;
        rowsum[idx] = 0.0f;
        if (idx < 1536)
            bcat[idx] = (idx < 512) ? bq[idx]
                      : (idx < 1024) ? bk[idx - 512] : bv[idx - 1024];
        return;
    }
    __shared__ bf16 tile[64][65];
    const float* W = (widx == 0) ? Wq : (widx == 1) ? Wk : (widx == 2) ? Wv : Wo;
    bf16* dst = (widx < 3) ? (Wcat + (size_t)widx * 512 * 512) : Wto;
    const int tx = blockIdx.x, ty = blockIdx.y;
#pragma unroll
    for (int it = 0; it < 16; ++it) {
        const int e = it * 256 + t0;
        const int r = e >> 6, c = e & 63;
        tile[r][c] = (bf16)W[(size_t)(ty * 64 + r) * 512 + tx * 64 + c];
    }
    __syncthreads();
#pragma unroll
    for (int it = 0; it < 16; ++it) {
        const int e = it * 256 + t0;
        const int o = e >> 6, i = e & 63;
        dst[(size_t)(tx * 64 + o) * 512 + ty * 64 + i] = tile[i][o];
    }
}

// ---------------------------------------------------------------------------
extern "C" void kernel_launch(void* const* d_in, const int* in_sizes, int n_in,
                              void* d_out, int out_size, void* d_ws, size_t ws_size,
                              hipStream_t stream)
{
    const float* x  = (const float*)d_in[0];
    const float* Wq = (const float*)d_in[1];
    const float* bq = (const float*)d_in[2];
    const float* Wk = (const float*)d_in[3];
    const float* bk = (const float*)d_in[4];
    const float* Wv = (const float*)d_in[5];
    const float* bv = (const float*)d_in[6];
    const float* Wo = (const float*)d_in[7];
    const float* bo = (const float*)d_in[8];
    float* out = (float*)d_out;

    char* ws = (char*)d_ws;
    bf16*    Xb     = (bf16*)(ws);              // 16 MB; dead after QKV GEMM
    bf16*    Ctx    = (bf16*)(ws);              // reuses Xb (attn output)
    bf16*    Wcat   = (bf16*)(ws + 16777216);   // 1536x512 bf16 (Wq^T|Wk^T|Wv^T)
    bf16*    Wto    = (bf16*)(ws + 18350080);   // 0.5 MB Wo^T
    float*   bcat   = (float*)(ws + 18874368);  // 1536 fp32 (bq|bk|bv)
    float*   rowsum = (float*)(ws + 18880512);  // 64 KB (zeroed; now unused)
    uint8_t* Q8     = (uint8_t*)(ws + 20971520);  // Q8|K8 fp8, 8 MB each
    uint8_t* K8     = (uint8_t*)(ws + 29360128);
    uint8_t* Vt8    = (uint8_t*)(ws + 54525952);  // [8][512][2048] fp8, 8 MB

    // prologue
    transpose4<<<dim3(8, 8, 5), 256, 0, stream>>>(
        Wq, Wk, Wv, Wo, Wcat, Wto, bq, bk, bv, bcat, rowsum);
    cvt_f32_bf16<<<8192, 256, 0, stream>>>(x, Xb, 2097152);

    const float scale = 0.044194173824159216f;  // 512^-0.5

    // Fused QKV projection (bf16 MFMA): Q8/K8 row-major fp8(x32), V written
    // transposed straight into Vt8 (no separate transpose dispatch).
    gemm_bt<3, 2><<<1536, 256, 0, stream>>>(
        Xb, Wcat, Q8, Vt8, bcat, 1536, 512, 12);

    // Fused attention: QK^T + exp + rowsum + PV + normalize -> Ctx (bf16)
    attn_fused<<<512, 256, 0, stream>>>(Q8, K8, Vt8, Ctx, scale / 1024.0f);

    // Out = Ctx @ Wo^T + bo (bf16 MFMA, fp32 out): M=16384, N=512, K=512
    gemm_bt<2, 2><<<512, 256, 0, stream>>>(
        Ctx, Wto, out, nullptr, bo, 512, 512, 4);
}

// Round 11
// 213.278 us; speedup vs baseline: 1.2396x; 1.2396x over previous
//
#include <hip/hip_runtime.h>
#include <hip/hip_bf16.h>
#include <hip/hip_fp8.h>
#include <stdint.h>

typedef __bf16 bf16;
typedef __attribute__((ext_vector_type(8))) short short8;
typedef __attribute__((ext_vector_type(4))) float f32x4;
typedef __attribute__((ext_vector_type(4))) bf16 bf16x4;
typedef __attribute__((ext_vector_type(8))) int int8v;
typedef __attribute__((ext_vector_type(4))) int int4v;

#define DIM 512
#define NBATCH 8
#define SEQ 2048

#define VMCNT(N) asm volatile("s_waitcnt vmcnt(" #N ")" ::: "memory")
#define CFENCE   asm volatile("" ::: "memory")

// async global->LDS, 16B per lane; LDS dest must be wave-uniform base + lane*16
__device__ __forceinline__ void gld_lds16(const void* g, void* l) {
    __builtin_amdgcn_global_load_lds(
        (const __attribute__((address_space(1))) void*)g,
        (__attribute__((address_space(3))) void*)l,
        16, 0, 0);
}

__device__ __forceinline__ unsigned char f32_to_e4m3(float v) {
#if __has_builtin(__builtin_amdgcn_cvt_pk_fp8_f32)
    return (unsigned char)(__builtin_amdgcn_cvt_pk_fp8_f32(v, v, 0, false) & 0xff);
#else
    return __hip_cvt_float_to_fp8(v, __HIP_SATFINITE, __HIP_E4M3);
#endif
}

// ---------------------------------------------------------------------------
// bf16 bt-GEMM: 128x128 tile, BK=64, double-buffered LDS (64 KB).
// R6-verified counted-vmcnt 2-barrier loop (worth ~12 us vs drain-0).
// MODE 2: C fp32 row-major [M][N], +bias  (out-projection).
// MODE 3: QKV split, all fp8(x32):
//         sub 0/1 (Q/K): row-major [16384][512] at Cv + sub*8388608.
//         sub 2 (V): written TRANSPOSED directly to Vt[(b*512+f)*2048+n].
// SWIZ 2: 1D grid, xcd=g&7; column-sibling blocks share an XCD (L2 reuse).
// ---------------------------------------------------------------------------
template <int MODE, int SWIZ>
__global__ __launch_bounds__(256) void gemm_bt(
    const bf16* __restrict__ A, const bf16* __restrict__ Bt,
    void* __restrict__ Cv, uint8_t* __restrict__ Vt,
    const float* __restrict__ bias, int N, int K, int gx)
{
    __shared__ bf16 smem[32768];         // 64 KB
    bf16* Asb = smem;
    bf16* Bsb = smem + 16384;

    int bx, by;
    {
        const unsigned g = blockIdx.x;
        const unsigned xcd = g & 7;
        const unsigned t = g >> 3;
        const unsigned per = (gridDim.x >> 3) / (unsigned)gx;
        by = xcd * per + t / (unsigned)gx;
        bx = t % (unsigned)gx;
    }

    const int tid  = threadIdx.x;
    const int lane = tid & 63;
    const int w    = tid >> 6;
    const int wr   = w >> 1;
    const int wc   = w & 1;
    const int lm   = lane & 15;
    const int lk   = lane >> 4;
    const int fs   = lm & 7;
    const int rq   = tid >> 3;
    const int pc   = tid & 7;
    const int scol = ((pc ^ (rq & 7)) * 8);

    const bf16* Ag = A + (size_t)(by * 128) * K;
    const bf16* Bg = Bt + (size_t)(bx * 128) * K;

    f32x4 acc[4][4];
#pragma unroll
    for (int i = 0; i < 4; ++i)
#pragma unroll
        for (int j = 0; j < 4; ++j)
            acc[i][j] = (f32x4){0.f, 0.f, 0.f, 0.f};

    auto stage = [&](int kb, int buf) {
#pragma unroll
        for (int t = 0; t < 4; ++t) {
            const int r = t * 32 + rq;
            gld_lds16(Ag + (size_t)r * K + kb + scol,
                      Asb + buf * 8192 + t * 2048 + tid * 8);
            gld_lds16(Bg + (size_t)r * K + kb + scol,
                      Bsb + buf * 8192 + t * 2048 + tid * 8);
        }
    };
    auto compute = [&](int buf) {
        const bf16* Ab = Asb + buf * 8192;
        const bf16* Bb = Bsb + buf * 8192;
#pragma unroll
        for (int s = 0; s < 2; ++s) {
            const int u = ((s * 4 + lk) ^ fs) * 8;
            short8 fa[4], fb[4];
#pragma unroll
            for (int i = 0; i < 4; ++i)
                fa[i] = *(const short8*)&Ab[(wr * 64 + i * 16 + lm) * 64 + u];
#pragma unroll
            for (int j = 0; j < 4; ++j)
                fb[j] = *(const short8*)&Bb[(wc * 64 + j * 16 + lm) * 64 + u];
#pragma unroll
            for (int i = 0; i < 4; ++i)
#pragma unroll
                for (int j = 0; j < 4; ++j)
                    acc[i][j] = __builtin_amdgcn_mfma_f32_16x16x32_bf16(
                        fa[i], fb[j], acc[i][j], 0, 0, 0);
        }
    };

    stage(0, 0);
    const int E = K >> 6;
#pragma unroll 2
    for (int e = 0; e < E; ++e) {
        const int p = e & 1;
        CFENCE;
        __builtin_amdgcn_s_barrier();    // WAR: buf p^1 readers done
        CFENCE;
        if (e + 1 < E) { stage((e + 1) << 6, p ^ 1); VMCNT(8); }
        else           { VMCNT(0); }
        CFENCE;
        __builtin_amdgcn_s_barrier();    // tile e published
        CFENCE;
        __builtin_amdgcn_s_setprio(1);
        compute(p);
        __builtin_amdgcn_s_setprio(0);
    }
    __syncthreads();                     // epilogue reuses smem

    // bias add
#pragma unroll
    for (int i = 0; i < 4; ++i)
#pragma unroll
        for (int j = 0; j < 4; ++j) {
            const int col = bx * 128 + wc * 64 + j * 16 + lm;
            const float bv = bias[col];
#pragma unroll
            for (int r = 0; r < 4; ++r)
                acc[i][j][r] += bv;
        }

    if (MODE == 2) {
        // fp32 out via LDS-coalesced float4 stores; ft = [64][132] floats
        float* ft = (float*)smem;
        float* outp = (float*)Cv;
#pragma unroll
        for (int h = 0; h < 2; ++h) {
            if (wr == h) {
#pragma unroll
                for (int i = 0; i < 4; ++i)
#pragma unroll
                    for (int j = 0; j < 4; ++j)
#pragma unroll
                        for (int r = 0; r < 4; ++r)
                            ft[(i * 16 + lk * 4 + r) * 132 + wc * 64 + j * 16 + lm] =
                                acc[i][j][r];
            }
            __syncthreads();
            const int rr = tid >> 5, cc = (tid & 31) * 4;
#pragma unroll
            for (int p = 0; p < 8; ++p) {
                const int row = p * 8 + rr;
                *(float4*)&outp[(size_t)(by * 128 + h * 64 + row) * N +
                                bx * 128 + cc] = *(const float4*)&ft[row * 132 + cc];
            }
            __syncthreads();
        }
        return;
    }

    // MODE 3
    const int sub  = (bx * 128) >> 9;          // 0=Q 1=K 2=V
    const int col0 = (bx * 128) & 511;

    if (sub == 2) {
        // V: transposed fp8 write -> Vt[(b*512 + col0+f)*2048 + n]
        const int b  = (by * 128) >> 11;
        const int n0 = (by * 128) & 2047;
        uint8_t* t8 = (uint8_t*)smem;
#pragma unroll
        for (int i = 0; i < 4; ++i)
#pragma unroll
            for (int j = 0; j < 4; ++j)
#pragma unroll
                for (int r = 0; r < 4; ++r) {
                    const int fl = wc * 64 + j * 16 + lm;      // feature
                    const int nl = wr * 64 + i * 16 + lk * 4 + r;  // token
                    t8[fl * 144 + nl] = f32_to_e4m3(32.0f * acc[i][j][r]);
                }
        __syncthreads();
        const int f = tid >> 1, nh = (tid & 1) * 64;
#pragma unroll
        for (int p = 0; p < 4; ++p) {
            const uint4 raw = *(const uint4*)&t8[f * 144 + nh + p * 16];
            *(uint4*)&Vt[((size_t)(b * 512 + col0 + f)) * 2048 +
                         n0 + nh + p * 16] = raw;
        }
        return;
    }

    // Q/K: row-major fp8 writer via LDS [64][144] tile halves
    uint8_t* d8 = (uint8_t*)Cv + (size_t)sub * 8388608;
    uint8_t* t8 = (uint8_t*)smem;
#pragma unroll
    for (int h = 0; h < 2; ++h) {
        if (wr == h) {
#pragma unroll
            for (int i = 0; i < 4; ++i)
#pragma unroll
                for (int j = 0; j < 4; ++j)
#pragma unroll
                    for (int r = 0; r < 4; ++r)
                        t8[(i * 16 + lk * 4 + r) * 144 + wc * 64 + j * 16 + lm] =
                            f32_to_e4m3(32.0f * acc[i][j][r]);
        }
        __syncthreads();
        const int rr = tid >> 3, cc = (tid & 7) * 16;
#pragma unroll
        for (int p = 0; p < 2; ++p) {
            const int row = p * 32 + rr;
            const uint4 raw = *(const uint4*)&t8[row * 144 + cc];
            *(uint4*)&d8[(size_t)(by * 128 + h * 64 + row) * 512 + col0 + cc] =
                raw;
        }
        __syncthreads();
    }
}

// ---------------------------------------------------------------------------
// MX fp8 bt-GEMM (attention): 128x128 tile, BK=128, double-buffered (64 KB),
// R4-VERIFIED 2-phase counted-vmcnt schedule (QK measured 50.0 us; byte-
// identical revert of R6's single-buffer regression, 59.6 us):
//   phase A: VMCNT(2); barrier; stage tile e+1 (A4,B02x2,B13x2);
//            ds_read fa; 8 MFMA (j=0,1)
//   phase B: VMCNT(8) [drains B13(e), leaves e+1's 8]; barrier;
//            8 MFMA (j=2,3)
// mfma_scale_f32_16x16x128_f8f6f4, unit e8m0 scales (127) = plain e4m3 GEMM.
// MODE 4 (E=4):  S8 = e4m3(exp(alpha*acc)); row sums atomicAdd into rsum.
// MODE 5 (E=16): C bf16 = acc / (32*rsum[row])  (PV + normalize).
// ---------------------------------------------------------------------------
template <int MODE, int E>
__global__ __launch_bounds__(256) void gemm_mx(
    const uint8_t* __restrict__ A, const uint8_t* __restrict__ Bt,
    void* __restrict__ Cv, float* __restrict__ rsum,
    int N, int K, long long sA, long long sB, long long sC, float alpha,
    int gx)
{
    __shared__ uint8_t smem[65536];
    uint8_t* Asb = smem;                 // two 16384-B buffers
    uint8_t* Bsb = smem + 32768;

    int bx, by, bz;
    {
        const unsigned g = blockIdx.x;
        bz = g & 7;
        const unsigned r = g >> 3;
        bx = r % (unsigned)gx;
        by = r / (unsigned)gx;
    }

    const int tid  = threadIdx.x;
    const int lane = tid & 63;
    const int w    = tid >> 6;
    const int wr   = w >> 1;
    const int wc   = w & 1;
    const int lm   = lane & 15;
    const int lk   = lane >> 4;
    const int rq   = tid >> 3;
    const int pc   = tid & 7;
    const int ssrc = (pc ^ (rq & 7)) * 16;
    const int ca   = ((2 * lk) ^ (lm & 7)) * 16;
    const int cb   = ((2 * lk + 1) ^ (lm & 7)) * 16;

    const size_t z = bz;
    const uint8_t* Ag = A + z * (size_t)sA + (size_t)(by * 128) * K;
    const uint8_t* Bg = Bt + z * (size_t)sB + (size_t)(bx * 128) * K;

    f32x4 acc[4][4];
#pragma unroll
    for (int i = 0; i < 4; ++i)
#pragma unroll
        for (int j = 0; j < 4; ++j)
            acc[i][j] = (f32x4){0.f, 0.f, 0.f, 0.f};

    // stage helpers: chunk t covers B rows t*32..t*32+31. Phase A consumes
    // fb[j=0,1] = rows {0..31 (t0), 64..95 (t2)}; phase B rows {t1, t3}.
    auto stageA = [&](int kb, int buf) {
#pragma unroll
        for (int t = 0; t < 4; ++t) {
            const int r = t * 32 + rq;
            gld_lds16(Ag + (size_t)r * K + kb + ssrc,
                      Asb + buf * 16384 + t * 4096 + tid * 16);
        }
    };
    auto stageB02 = [&](int kb, int buf) {
#pragma unroll
        for (int t = 0; t < 4; t += 2) {
            const int r = t * 32 + rq;
            gld_lds16(Bg + (size_t)r * K + kb + ssrc,
                      Bsb + buf * 16384 + t * 4096 + tid * 16);
        }
    };
    auto stageB13 = [&](int kb, int buf) {
#pragma unroll
        for (int t = 1; t < 4; t += 2) {
            const int r = t * 32 + rq;
            gld_lds16(Bg + (size_t)r * K + kb + ssrc,
                      Bsb + buf * 16384 + t * 4096 + tid * 16);
        }
    };
    auto loadB = [&](const uint8_t* Bs, int j) -> int8v {
        const uint8_t* rp = Bs + (wc * 64 + j * 16 + lm) * 128;
        const int4v lo = *(const int4v*)(rp + ca);
        const int4v hi = *(const int4v*)(rp + cb);
        return (int8v){lo[0], lo[1], lo[2], lo[3], hi[0], hi[1], hi[2], hi[3]};
    };

    // prologue: tile 0 fully in flight (A,B02 older; B13 newest 2)
    stageA(0, 0); stageB02(0, 0); stageB13(0, 0);

#pragma unroll
    for (int e = 0; e < E; ++e) {
        const int p = e & 1;
        const uint8_t* As = Asb + p * 16384;
        const uint8_t* Bs = Bsb + p * 16384;

        // ---- phase A: needs A(e), B02(e) ----
        VMCNT(2);
        __builtin_amdgcn_s_barrier();
        if (e + 1 < E) {
            stageA((e + 1) * 128, p ^ 1);
            stageB02((e + 1) * 128, p ^ 1);
            stageB13((e + 1) * 128, p ^ 1);
        }
        int8v fa[4];
#pragma unroll
        for (int i = 0; i < 4; ++i) {
            const uint8_t* rp = As + (wr * 64 + i * 16 + lm) * 128;
            const int4v lo = *(const int4v*)(rp + ca);
            const int4v hi = *(const int4v*)(rp + cb);
            fa[i] = (int8v){lo[0], lo[1], lo[2], lo[3],
                            hi[0], hi[1], hi[2], hi[3]};
        }
        __builtin_amdgcn_s_setprio(1);
#pragma unroll
        for (int j = 0; j < 2; ++j) {
            const int8v fb = loadB(Bs, j);
#pragma unroll
            for (int i = 0; i < 4; ++i)
                acc[i][j] = __builtin_amdgcn_mfma_scale_f32_16x16x128_f8f6f4(
                    fa[i], fb, acc[i][j], 0, 0, 0, 127, 0, 127);
        }
        __builtin_amdgcn_s_setprio(0);

        // ---- phase B: needs B13(e) ----
        if (e + 1 < E) { VMCNT(8); } else { VMCNT(0); }
        __builtin_amdgcn_s_barrier();
        __builtin_amdgcn_s_setprio(1);
#pragma unroll
        for (int j = 2; j < 4; ++j) {
            const int8v fb = loadB(Bs, j);
#pragma unroll
            for (int i = 0; i < 4; ++i)
                acc[i][j] = __builtin_amdgcn_mfma_scale_f32_16x16x128_f8f6f4(
                    fa[i], fb, acc[i][j], 0, 0, 0, 127, 0, 127);
        }
        __builtin_amdgcn_s_setprio(0);
    }
    __syncthreads();   // epilogue reuses smem

    const int orow0 = by * 128 + wr * 64;

    if (MODE == 4) {
#pragma unroll
        for (int i = 0; i < 4; ++i) {
            float psum[4] = {0.f, 0.f, 0.f, 0.f};
#pragma unroll
            for (int j = 0; j < 4; ++j)
#pragma unroll
                for (int r = 0; r < 4; ++r) {
                    const float e = __expf(acc[i][j][r] * alpha);
                    acc[i][j][r] = e;
                    psum[r] += e;
                }
#pragma unroll
            for (int m = 1; m < 16; m <<= 1)
#pragma unroll
                for (int r = 0; r < 4; ++r) psum[r] += __shfl_xor(psum[r], m);
            if (lm == 0) {
#pragma unroll
                for (int r = 0; r < 4; ++r)
                    atomicAdd(&rsum[z * SEQ + orow0 + i * 16 + lk * 4 + r],
                              psum[r]);
            }
        }
        uint8_t* dst = (uint8_t*)Cv + z * (size_t)sC;
#pragma unroll
        for (int h = 0; h < 2; ++h) {
            if (wr == h) {
#pragma unroll
                for (int i = 0; i < 4; ++i)
#pragma unroll
                    for (int j = 0; j < 4; ++j)
#pragma unroll
                        for (int r = 0; r < 4; ++r)
                            smem[(i * 16 + lk * 4 + r) * 144 +
                                 wc * 64 + j * 16 + lm] =
                                f32_to_e4m3(acc[i][j][r]);
            }
            __syncthreads();
            const int rr = tid >> 3, cc = (tid & 7) * 16;
#pragma unroll
            for (int p = 0; p < 2; ++p) {
                const int row = p * 32 + rr;
                const uint4 raw = *(const uint4*)&smem[row * 144 + cc];
                *(uint4*)&dst[(size_t)(by * 128 + h * 64 + row) * N +
                              bx * 128 + cc] = raw;
            }
            __syncthreads();
        }
        return;
    }

    // MODE 5: normalize by 32*rowsum, bf16 out via LDS [64][136] tile
#pragma unroll
    for (int i = 0; i < 4; ++i) {
        float inv[4];
#pragma unroll
        for (int r = 0; r < 4; ++r)
            inv[r] = 1.0f / (32.0f * rsum[z * SEQ + orow0 + i * 16 + lk * 4 + r]);
#pragma unroll
        for (int j = 0; j < 4; ++j)
#pragma unroll
            for (int r = 0; r < 4; ++r)
                acc[i][j][r] *= inv[r];
    }
    bf16* dst = (bf16*)Cv + z * (size_t)sC;
    bf16* tile = (bf16*)smem;
#pragma unroll
    for (int h = 0; h < 2; ++h) {
        if (wr == h) {
#pragma unroll
            for (int i = 0; i < 4; ++i)
#pragma unroll
                for (int j = 0; j < 4; ++j)
#pragma unroll
                    for (int r = 0; r < 4; ++r)
                        tile[(i * 16 + lk * 4 + r) * 136 + wc * 64 + j * 16 + lm] =
                            (bf16)acc[i][j][r];
        }
        __syncthreads();
        const int rr0 = tid >> 4, cc = (tid & 15) * 8;
#pragma unroll
        for (int p = 0; p < 4; ++p) {
            const int row = p * 16 + rr0;
            const uint4 raw = *(const uint4*)&tile[row * 136 + cc];
            *(uint4*)&dst[(size_t)(by * 128 + h * 64 + row) * N + bx * 128 + cc] =
                raw;
        }
        __syncthreads();
    }
}

// ---------------------------------------------------------------------------
__global__ __launch_bounds__(256) void cvt_f32_bf16(
    const float* __restrict__ x, bf16* __restrict__ o, int n4)
{
    const int i = blockIdx.x * 256 + threadIdx.x;
    if (i >= n4) return;
    const float4 v = ((const float4*)x)[i];
    bf16x4 b;
    b[0] = (bf16)v.x; b[1] = (bf16)v.y; b[2] = (bf16)v.z; b[3] = (bf16)v.w;
    ((bf16x4*)o)[i] = b;
}

// Weights transpose -> bf16; z==4 slice zeroes rowsum + packs bcat=bq|bk|bv.
__global__ __launch_bounds__(256) void transpose4(
    const float* __restrict__ Wq, const float* __restrict__ Wk,
    const float* __restrict__ Wv, const float* __restrict__ Wo,
    bf16* __restrict__ Wcat, bf16* __restrict__ Wto,
    const float* __restrict__ bq, const float* __restrict__ bk,
    const float* __restrict__ bv, float* __restrict__ bcat,
    float* __restrict__ rowsum)
{
    const int widx = blockIdx.z;
    const int t0 = threadIdx.x;
    if (widx == 4) {
        const int idx = (blockIdx.y * 8 + blockIdx.x) * 256 + t0;
        rowsum[idx] = 0.0f;
        if (idx < 1536)
            bcat[idx] = (idx < 512) ? bq[idx]
                      : (idx < 1024) ? bk[idx - 512] : bv[idx - 1024];
        return;
    }
    __shared__ bf16 tile[64][65];
    const float* W = (widx == 0) ? Wq : (widx == 1) ? Wk : (widx == 2) ? Wv : Wo;
    bf16* dst = (widx < 3) ? (Wcat + (size_t)widx * 512 * 512) : Wto;
    const int tx = blockIdx.x, ty = blockIdx.y;
#pragma unroll
    for (int it = 0; it < 16; ++it) {
        const int e = it * 256 + t0;
        const int r = e >> 6, c = e & 63;
        tile[r][c] = (bf16)W[(size_t)(ty * 64 + r) * 512 + tx * 64 + c];
    }
    __syncthreads();
#pragma unroll
    for (int it = 0; it < 16; ++it) {
        const int e = it * 256 + t0;
        const int o = e >> 6, i = e & 63;
        dst[(size_t)(tx * 64 + o) * 512 + ty * 64 + i] = tile[i][o];
    }
}

// ---------------------------------------------------------------------------
extern "C" void kernel_launch(void* const* d_in, const int* in_sizes, int n_in,
                              void* d_out, int out_size, void* d_ws, size_t ws_size,
                              hipStream_t stream)
{
    const float* x  = (const float*)d_in[0];
    const float* Wq = (const float*)d_in[1];
    const float* bq = (const float*)d_in[2];
    const float* Wk = (const float*)d_in[3];
    const float* bk = (const float*)d_in[4];
    const float* Wv = (const float*)d_in[5];
    const float* bv = (const float*)d_in[6];
    const float* Wo = (const float*)d_in[7];
    const float* bo = (const float*)d_in[8];
    float* out = (float*)d_out;

    char* ws = (char*)d_ws;
    bf16*    Xb     = (bf16*)(ws);              // 16 MB; dead after QKV GEMM
    bf16*    Ctx    = (bf16*)(ws);              // reuses Xb (PV output)
    bf16*    Wcat   = (bf16*)(ws + 16777216);   // 1536x512 bf16 (Wq^T|Wk^T|Wv^T)
    bf16*    Wto    = (bf16*)(ws + 18350080);   // 0.5 MB Wo^T
    float*   bcat   = (float*)(ws + 18874368);  // 1536 fp32 (bq|bk|bv)
    float*   rowsum = (float*)(ws + 18880512);  // 64 KB
    uint8_t* Q8     = (uint8_t*)(ws + 20971520);  // Q8|K8 fp8, 8 MB each
    uint8_t* K8     = (uint8_t*)(ws + 29360128);
    uint8_t* Vt8    = (uint8_t*)(ws + 54525952);  // [8][512][2048] fp8, 8 MB
    uint8_t* S8     = (uint8_t*)(ws + 62914560);  // [8][2048][2048] fp8, 33.5 MB

    // prologue
    transpose4<<<dim3(8, 8, 5), 256, 0, stream>>>(
        Wq, Wk, Wv, Wo, Wcat, Wto, bq, bk, bv, bcat, rowsum);
    cvt_f32_bf16<<<8192, 256, 0, stream>>>(x, Xb, 2097152);

    const float scale = 0.044194173824159216f;  // 512^-0.5

    // Fused QKV projection (bf16 MFMA): Q8/K8 row-major fp8(x32), V written
    // transposed straight into Vt8 (no separate transpose dispatch).
    gemm_bt<3, 2><<<1536, 256, 0, stream>>>(
        Xb, Wcat, Q8, Vt8, bcat, 1536, 512, 12);

    // S8 = e4m3(exp(scale/1024 * Q8 @ K8^T)) + row sums; per batch 2048x2048
    gemm_mx<4, 4><<<2048, 256, 0, stream>>>(
        Q8, K8, S8, rowsum, 2048, 512,
        2048LL * 512, 2048LL * 512, 2048LL * 2048, scale / 1024.0f, 16);

    // Ctx = (S8 @ Vt8^T) / (32*rowsum): per batch M=2048, N=512, K=2048
    gemm_mx<5, 16><<<512, 256, 0, stream>>>(
        S8, Vt8, Ctx, rowsum, 512, 2048,
        2048LL * 2048, 512LL * 2048, 2048LL * 512, 1.0f, 4);

    // Out = Ctx @ Wo^T + bo (bf16 MFMA, fp32 out): M=16384, N=512, K=512
    gemm_bt<2, 2><<<512, 256, 0, stream>>>(
        Ctx, Wto, out, nullptr, bo, 512, 512, 4);
}